// Round 15
// baseline (820.846 us; speedup 1.0000x reference)
//
#include <hip/hip_runtime.h>
#include <hip/hip_fp16.h>
#include <math.h>

#define NB 256
#define HDIM 256
#define NHEADS 4
#define DKH 64
#define LA 127
#define LP 23
#define LH 11

typedef _Float16 h2v __attribute__((ext_vector_type(2)));
typedef _Float16 f16x8 __attribute__((ext_vector_type(8)));
typedef float f32x4 __attribute__((ext_vector_type(4)));
union F4H { float4 f4; h2v h[4]; };

__device__ __forceinline__ float dot2acc(h2v a, h2v b, float c) {
#if __has_builtin(__builtin_amdgcn_fdot2)
  return __builtin_amdgcn_fdot2(a, b, c, false);
#else
  return c + (float)a[0] * (float)b[0] + (float)a[1] * (float)b[1];
#endif
}

__device__ __forceinline__ float sigm(float x) { return 1.0f / (1.0f + __expf(-x)); }
__device__ __forceinline__ float tanh_fast(float x) { return 2.0f / (1.0f + __expf(-2.0f * x)) - 1.0f; }

// ---------- ONE prep kernel: scan + Whh cvt x2 + Wih frag-pack x2 + proj hi/lo pack x2 ----------
__global__ void k_prep(const int* __restrict__ ac, const int* __restrict__ pc,
                       const int* __restrict__ hc, int* __restrict__ sa,
                       int* __restrict__ sp, int* __restrict__ sh,
                       const float* __restrict__ Whh_f, __half* __restrict__ Wh16_f,
                       const float* __restrict__ Whh_b, __half* __restrict__ Wh16_b,
                       const float* __restrict__ Wih_f, __half* __restrict__ Wf16_f,
                       const float* __restrict__ Wih_b, __half* __restrict__ Wf16_b,
                       const float* __restrict__ Wq, __half* __restrict__ Wqh,
                       __half* __restrict__ Wql, const float* __restrict__ Wo,
                       __half* __restrict__ Woh, __half* __restrict__ Wol) {
  const int NT = 768 * 256, NP = 256 * 256;
  if (blockIdx.x == gridDim.x - 1) {
    int t = threadIdx.x;
    if (t == 0) { int s = 0; for (int i = 0; i < NB; i++) { sa[i] = s; s += ac[i]; } }
    else if (t == 1) { int s = 0; for (int i = 0; i < NB; i++) { sp[i] = s; s += pc[i]; } }
    else if (t == 2) { int s = 0; for (int i = 0; i < NB; i++) { sh[i] = s; s += hc[i]; } }
    return;
  }
  int idx = blockIdx.x * 256 + threadIdx.x;
  if (idx < NT) { Wh16_f[idx] = __float2half(Whh_f[idx]); return; }
  idx -= NT;
  if (idx < NT) { Wh16_b[idx] = __float2half(Whh_b[idx]); return; }
  idx -= NT;
  if (idx < NT) {
    int u = idx & 7, lg = (idx >> 3) & 3, c = (idx >> 5) % 768, k0b = (idx >> 5) / 768;
    Wf16_f[idx] = __float2half(Wih_f[(size_t)c * 256 + k0b * 32 + lg * 8 + u]);
    return;
  }
  idx -= NT;
  if (idx < NT) {
    int u = idx & 7, lg = (idx >> 3) & 3, c = (idx >> 5) % 768, k0b = (idx >> 5) / 768;
    Wf16_b[idx] = __float2half(Wih_b[(size_t)c * 256 + k0b * 32 + lg * 8 + u]);
    return;
  }
  idx -= NT;
  if (idx < NP) {
    int u = idx & 7, lg = (idx >> 3) & 3, c = (idx >> 5) & 255, k0b = idx >> 13;
    float w = Wq[(size_t)(k0b * 32 + lg * 8 + u) * 256 + c];
    __half h = __float2half(w);
    Wqh[idx] = h; Wql[idx] = __float2half(w - __half2float(h));
    return;
  }
  idx -= NP;
  if (idx < NP) {
    int u = idx & 7, lg = (idx >> 3) & 3, c = (idx >> 5) & 255, k0b = idx >> 13;
    float w = Wo[(size_t)(k0b * 32 + lg * 8 + u) * 256 + c];
    __half h = __float2half(w);
    Woh[idx] = h; Wol[idx] = __float2half(w - __half2float(h));
  }
}

// ---------- gather (split_batch) + hi/lo split (round-11 proven) ----------
__global__ void k_gsplit(const float* __restrict__ msg, const int* __restrict__ starts,
                         const int* __restrict__ counts, int L, int M,
                         __half* __restrict__ hi, __half* __restrict__ lo) {
  int idx = blockIdx.x * blockDim.x + threadIdx.x;
  if (idx >= M * 256) return;
  int r = idx >> 8, c = idx & 255;
  int b = r / L, t = r - b * L;
  float v = (t < counts[b]) ? msg[(size_t)(starts[b] + t) * 256 + c] : 0.f;
  __half h = __float2half(v);
  hi[idx] = h;
  lo[idx] = __float2half(v - __half2float(h));
}

// ---------- generic fp32 GEMM (Ch!=null adds fp16 mirror) ----------
template <bool GATHER_A, bool RES_GATHER>
__global__ __launch_bounds__(256) void k_gemm(
    const float* __restrict__ A, const float* __restrict__ msg,
    const int* __restrict__ starts, const int* __restrict__ counts, int L,
    const float* __restrict__ W, const float* __restrict__ bias,
    const float* __restrict__ resmsg, float* __restrict__ C,
    __half* __restrict__ Ch, int N) {
  const int K = HDIM;
  __shared__ float As[16][76];
  __shared__ float Ws[16][72];
  int tid = threadIdx.x;
  int row0 = blockIdx.x * 64, col0 = blockIdx.y * 64;
  int arow = row0 + (tid >> 2);
  const float* asrc;
  if constexpr (GATHER_A) {
    int b = arow / L, t = arow - b * L;
    asrc = (t < counts[b]) ? (msg + (size_t)(starts[b] + t) * K) : nullptr;
  } else {
    asrc = A + (size_t)arow * K;
  }
  int ak = (tid & 3) * 4;
  int wk = tid >> 4, wn = (tid & 15) * 4;
  int ty = tid >> 4, tx = tid & 15;
  float acc[4][4] = {};
  for (int k0 = 0; k0 < K; k0 += 16) {
    float4 av = make_float4(0.f, 0.f, 0.f, 0.f);
    if (asrc) av = *(const float4*)(asrc + k0 + ak);
    float4 wv = *(const float4*)(W + (size_t)(k0 + wk) * N + col0 + wn);
    __syncthreads();
    int m = tid >> 2;
    As[ak + 0][m] = av.x; As[ak + 1][m] = av.y;
    As[ak + 2][m] = av.z; As[ak + 3][m] = av.w;
    *(float4*)&Ws[wk][wn] = wv;
    __syncthreads();
#pragma unroll
    for (int kk = 0; kk < 16; kk++) {
      float4 a = *(const float4*)&As[kk][ty * 4];
      float4 b = *(const float4*)&Ws[kk][tx * 4];
      acc[0][0] += a.x * b.x; acc[0][1] += a.x * b.y; acc[0][2] += a.x * b.z; acc[0][3] += a.x * b.w;
      acc[1][0] += a.y * b.x; acc[1][1] += a.y * b.y; acc[1][2] += a.y * b.z; acc[1][3] += a.y * b.w;
      acc[2][0] += a.z * b.x; acc[2][1] += a.z * b.y; acc[2][2] += a.z * b.z; acc[2][3] += a.z * b.w;
      acc[3][0] += a.w * b.x; acc[3][1] += a.w * b.y; acc[3][2] += a.w * b.z; acc[3][3] += a.w * b.w;
    }
  }
  float4 bv = *(const float4*)(bias + col0 + tx * 4);
#pragma unroll
  for (int i = 0; i < 4; i++) {
    int r = row0 + ty * 4 + i;
    float o0 = acc[i][0] + bv.x, o1 = acc[i][1] + bv.y,
          o2 = acc[i][2] + bv.z, o3 = acc[i][3] + bv.w;
    if constexpr (RES_GATHER) {
      int b = r / L, t = r - b * L;
      if (t < counts[b]) {
        float4 rv = *(const float4*)(resmsg + (size_t)(starts[b] + t) * K + col0 + tx * 4);
        o0 += rv.x; o1 += rv.y; o2 += rv.z; o3 += rv.w;
      }
    }
    size_t o = (size_t)r * N + col0 + tx * 4;
    *(float4*)(C + o) = make_float4(o0, o1, o2, o3);
    if (Ch) {
      Ch[o] = __float2half(o0); Ch[o + 1] = __float2half(o1);
      Ch[o + 2] = __float2half(o2); Ch[o + 3] = __float2half(o3);
    }
  }
}

// ---------- dual-output fp32 GEMM (blockIdx.z selects {W,bias,C}) ----------
template <bool GATHER_A>
__global__ __launch_bounds__(256) void k_gemm_kv(
    const float* __restrict__ A, const float* __restrict__ msg,
    const int* __restrict__ starts, const int* __restrict__ counts, int L,
    const float* __restrict__ W0, const float* __restrict__ b0, float* __restrict__ C0,
    const float* __restrict__ W1, const float* __restrict__ b1, float* __restrict__ C1) {
  const int K = HDIM, N = HDIM;
  const float* W = blockIdx.z ? W1 : W0;
  const float* bias = blockIdx.z ? b1 : b0;
  float* C = blockIdx.z ? C1 : C0;
  __shared__ float As[16][76];
  __shared__ float Ws[16][72];
  int tid = threadIdx.x;
  int row0 = blockIdx.x * 64, col0 = blockIdx.y * 64;
  int arow = row0 + (tid >> 2);
  const float* asrc;
  if constexpr (GATHER_A) {
    int b = arow / L, t = arow - b * L;
    asrc = (t < counts[b]) ? (msg + (size_t)(starts[b] + t) * K) : nullptr;
  } else {
    asrc = A + (size_t)arow * K;
  }
  int ak = (tid & 3) * 4;
  int wk = tid >> 4, wn = (tid & 15) * 4;
  int ty = tid >> 4, tx = tid & 15;
  float acc[4][4] = {};
  for (int k0 = 0; k0 < K; k0 += 16) {
    float4 av = make_float4(0.f, 0.f, 0.f, 0.f);
    if (asrc) av = *(const float4*)(asrc + k0 + ak);
    float4 wv = *(const float4*)(W + (size_t)(k0 + wk) * N + col0 + wn);
    __syncthreads();
    int m = tid >> 2;
    As[ak + 0][m] = av.x; As[ak + 1][m] = av.y;
    As[ak + 2][m] = av.z; As[ak + 3][m] = av.w;
    *(float4*)&Ws[wk][wn] = wv;
    __syncthreads();
#pragma unroll
    for (int kk = 0; kk < 16; kk++) {
      float4 a = *(const float4*)&As[kk][ty * 4];
      float4 b = *(const float4*)&Ws[kk][tx * 4];
      acc[0][0] += a.x * b.x; acc[0][1] += a.x * b.y; acc[0][2] += a.x * b.z; acc[0][3] += a.x * b.w;
      acc[1][0] += a.y * b.x; acc[1][1] += a.y * b.y; acc[1][2] += a.y * b.z; acc[1][3] += a.y * b.w;
      acc[2][0] += a.z * b.x; acc[2][1] += a.z * b.y; acc[2][2] += a.z * b.z; acc[2][3] += a.z * b.w;
      acc[3][0] += a.w * b.x; acc[3][1] += a.w * b.y; acc[3][2] += a.w * b.z; acc[3][3] += a.w * b.w;
    }
  }
  float4 bv = *(const float4*)(bias + col0 + tx * 4);
#pragma unroll
  for (int i = 0; i < 4; i++) {
    int r = row0 + ty * 4 + i;
    size_t o = (size_t)r * N + col0 + tx * 4;
    *(float4*)(C + o) = make_float4(acc[i][0] + bv.x, acc[i][1] + bv.y,
                                    acc[i][2] + bv.z, acc[i][3] + bv.w);
  }
}

// ---------- split-fp16 MFMA GEMM (round-11 proven numerics; + optional fp16 mirror) ----------
template <bool RES>
__global__ __launch_bounds__(256) void k_mfma_sp(
    const __half* __restrict__ Ahi, const __half* __restrict__ Alo,
    const __half* __restrict__ Whi, const __half* __restrict__ Wlo,
    const float* __restrict__ bias, const float* __restrict__ resmsg,
    const int* __restrict__ starts, const int* __restrict__ counts, int L,
    float* __restrict__ Out, __half* __restrict__ Ch) {
  int w = threadIdx.x >> 6, l = threadIdx.x & 63;
  int row0 = blockIdx.x * 64 + w * 16;
  int col0 = blockIdx.y * 64;
  int lr = l & 15, lg = l >> 4;
  f32x4 acc[4] = {};
  const __half* ahrow = Ahi + (size_t)(row0 + lr) * 256 + lg * 8;
  const __half* alrow = Alo + (size_t)(row0 + lr) * 256 + lg * 8;
#pragma unroll
  for (int k0b = 0; k0b < 8; k0b++) {
    f16x8 ah = *(const f16x8*)(ahrow + k0b * 32);
    f16x8 al = *(const f16x8*)(alrow + k0b * 32);
#pragma unroll
    for (int nt = 0; nt < 4; nt++) {
      int c = col0 + nt * 16 + lr;
      size_t wi = ((size_t)(k0b * 256 + c) * 4 + lg) * 8;
      f16x8 bh = *(const f16x8*)(Whi + wi);
      f16x8 bl = *(const f16x8*)(Wlo + wi);
      acc[nt] = __builtin_amdgcn_mfma_f32_16x16x32_f16(ah, bh, acc[nt], 0, 0, 0);
      acc[nt] = __builtin_amdgcn_mfma_f32_16x16x32_f16(al, bh, acc[nt], 0, 0, 0);
      acc[nt] = __builtin_amdgcn_mfma_f32_16x16x32_f16(ah, bl, acc[nt], 0, 0, 0);
    }
  }
#pragma unroll
  for (int nt = 0; nt < 4; nt++) {
    int c = col0 + nt * 16 + lr;
    float bv = bias[c];
#pragma unroll
    for (int r = 0; r < 4; r++) {
      int row = row0 + lg * 4 + r;
      float o = acc[nt][r] + bv;
      if constexpr (RES) {
        int b = row / L, t = row - b * L;
        if (t < counts[b]) o += resmsg[(size_t)(starts[b] + t) * 256 + c];
      }
      size_t oidx = (size_t)row * 256 + c;
      Out[oidx] = o;
      if (Ch) Ch[oidx] = __float2half(o);
    }
  }
}

// ---------- fused dual MFMA fp16 GEMM for gi ----------
__global__ __launch_bounds__(256) void k_mfma_gi2(
    const __half* __restrict__ A16,
    const __half* __restrict__ Wf_f, const __half* __restrict__ Wf_b,
    const float* __restrict__ bias_f, const float* __restrict__ bias_b,
    __half* __restrict__ Out_f, __half* __restrict__ Out_b) {
  const int N = 768;
  int y = blockIdx.y;
  const __half* Wf = y < 12 ? Wf_f : Wf_b;
  const float* bias = y < 12 ? bias_f : bias_b;
  __half* Out = y < 12 ? Out_f : Out_b;
  int col0 = (y < 12 ? y : y - 12) * 64;
  int w = threadIdx.x >> 6, l = threadIdx.x & 63;
  int row0 = blockIdx.x * 64 + w * 16;
  int lr = l & 15, lg = l >> 4;
  f32x4 acc[4] = {};
  const __half* arow = A16 + (size_t)(row0 + lr) * 256 + lg * 8;
#pragma unroll
  for (int k0b = 0; k0b < 8; k0b++) {
    f16x8 a = *(const f16x8*)(arow + k0b * 32);
#pragma unroll
    for (int nt = 0; nt < 4; nt++) {
      int c = col0 + nt * 16 + lr;
      f16x8 b = *(const f16x8*)(Wf + ((size_t)(k0b * N + c) * 4 + lg) * 8);
      acc[nt] = __builtin_amdgcn_mfma_f32_16x16x32_f16(a, b, acc[nt], 0, 0, 0);
    }
  }
#pragma unroll
  for (int nt = 0; nt < 4; nt++) {
    int c = col0 + nt * 16 + lr;
    float bv = bias[c];
#pragma unroll
    for (int r = 0; r < 4; r++) {
      int row = row0 + lg * 4 + r;
      Out[(size_t)row * N + c] = __float2half(acc[nt][r] + bv);
    }
  }
}

// ---------- attention: q-row in registers, float4 LDS reads ----------
// SPLITOUT: also emit hi/lo fp16 of the output (feeds split-fp16 o-proj).
template <int LQ, int LK, bool SPLITOUT>
__global__ __launch_bounds__(128) void k_attn(
    float* __restrict__ q, const float* __restrict__ kbuf,
    const float* __restrict__ vbuf, const int* __restrict__ cq,
    const int* __restrict__ ck, __half* __restrict__ oh, __half* __restrict__ ol) {
  __shared__ float qs[LQ][65];
  __shared__ float ks[LK][65];
  __shared__ float vs[LK][65];
  int b = blockIdx.x, head = blockIdx.y;
  int tid = threadIdx.x;
  for (int idx = tid; idx < LQ * 16; idx += 128) {
    int i = idx >> 4, c = (idx & 15) * 4;
    float4 v = *(const float4*)(q + (size_t)(b * LQ + i) * HDIM + head * DKH + c);
    qs[i][c] = v.x; qs[i][c + 1] = v.y; qs[i][c + 2] = v.z; qs[i][c + 3] = v.w;
  }
  for (int idx = tid; idx < LK * 16; idx += 128) {
    int i = idx >> 4, c = (idx & 15) * 4;
    float4 v = *(const float4*)(kbuf + (size_t)(b * LK + i) * HDIM + head * DKH + c);
    ks[i][c] = v.x; ks[i][c + 1] = v.y; ks[i][c + 2] = v.z; ks[i][c + 3] = v.w;
    float4 w = *(const float4*)(vbuf + (size_t)(b * LK + i) * HDIM + head * DKH + c);
    vs[i][c] = w.x; vs[i][c + 1] = w.y; vs[i][c + 2] = w.z; vs[i][c + 3] = w.w;
  }
  __syncthreads();
  int nq = cq[b], nk = ck[b];
  for (int i = tid; i < LQ; i += 128) {
    float4 qr[16];
#pragma unroll
    for (int c4 = 0; c4 < 16; c4++) qr[c4] = *(const float4*)&qs[i][c4 * 4];
    float s[LK];
    float mx = -INFINITY;
    bool qv = i < nq;
#pragma unroll
    for (int k = 0; k < LK; k++) {
      float d = -1e9f;
      if (qv && k < nk) {
        float acc = 0.f;
#pragma unroll
        for (int c4 = 0; c4 < 16; c4++) {
          float4 kv = *(const float4*)&ks[k][c4 * 4];
          acc += qr[c4].x * kv.x + qr[c4].y * kv.y + qr[c4].z * kv.z + qr[c4].w * kv.w;
        }
        d = acc * 0.125f;
      }
      s[k] = d;
      mx = fmaxf(mx, d);
    }
    float den = 0.f;
#pragma unroll
    for (int k = 0; k < LK; k++) { s[k] = expf(s[k] - mx); den += s[k]; }
    float inv = 1.0f / den;
#pragma unroll
    for (int c4 = 0; c4 < 16; c4++) {
      float4 a = make_float4(0.f, 0.f, 0.f, 0.f);
#pragma unroll
      for (int k = 0; k < LK; k++) {
        float4 vv = *(const float4*)&vs[k][c4 * 4];
        a.x += s[k] * vv.x; a.y += s[k] * vv.y;
        a.z += s[k] * vv.z; a.w += s[k] * vv.w;
      }
      a.x *= inv; a.y *= inv; a.z *= inv; a.w *= inv;
      size_t o = (size_t)(b * LQ + i) * HDIM + head * DKH + c4 * 4;
      *(float4*)(q + o) = a;
      if constexpr (SPLITOUT) {
        float vals[4] = {a.x, a.y, a.z, a.w};
#pragma unroll
        for (int u = 0; u < 4; u++) {
          __half h = __float2half(vals[u]);
          oh[o + u] = h;
          ol[o + u] = __float2half(vals[u] - __half2float(h));
        }
      }
    }
  }
}

// ---------- GRU v4 + fused rowmax prologue (bitwise-identical h0) ----------
__global__ __launch_bounds__(512, 2) void k_gru4(
    const float* __restrict__ h_x, const __half* __restrict__ Wh_f,
    const __half* __restrict__ Wh_b, const __half* __restrict__ gi_f,
    const __half* __restrict__ gi_b, const float* __restrict__ bhh_f,
    const float* __restrict__ bhh_b, const int* __restrict__ ac,
    float* __restrict__ out) {
  int bid = blockIdx.x;
  int dir = bid & 1, pair = bid >> 1;
  int g0 = pair, g1 = pair + 128;
  int tid = threadIdx.x;
  int j = tid >> 1, half = tid & 1;
  const __half* W = dir ? Wh_b : Wh_f;
  const __half* gih = dir ? gi_b : gi_f;
  const float* bhh = dir ? bhh_b : bhh_f;

  // fused rowmax: h0[g][j] = max_t h_x[g][t][j] (incl. padded rows)
  __shared__ float h0s[2][HDIM];
  {
    int g = tid >> 8, jj = tid & 255;
    int gg = g ? g1 : g0;
    const float* hp_ = h_x + (size_t)gg * LA * HDIM + jj;
    float m = -INFINITY;
    for (int t = 0; t < LA; t++) m = fmaxf(m, hp_[(size_t)t * HDIM]);
    h0s[g][jj] = m;
  }

  F4H wr[16], wz[16], wn[16];
  {
    const float4* Wr4 = (const float4*)(W + (size_t)j * 256 + half * 128);
    const float4* Wz4 = (const float4*)(W + (size_t)(256 + j) * 256 + half * 128);
    const float4* Wn4 = (const float4*)(W + (size_t)(512 + j) * 256 + half * 128);
#pragma unroll
    for (int p = 0; p < 16; p++) wr[p].f4 = Wr4[p];
#pragma unroll
    for (int p = 0; p < 16; p++) wz[p].f4 = Wz4[p];
#pragma unroll
    for (int p = 0; p < 16; p++) wn[p].f4 = Wn4[p];
  }
  float br = bhh[j], bz = bhh[256 + j], bn = bhh[512 + j];
  int cnt = ac[g0];

  __syncthreads();
  __shared__ __align__(16) __half hs[2][HDIM];
  float hprev0 = h0s[0][j];
  float hprev1 = h0s[1][j];
  if (half == 0) {
    hs[0][j] = __float2half(hprev0);
    hs[1][j] = __float2half(hprev1);
  }
  __syncthreads();

  const float4* h0p = (const float4*)hs[0] + half * 16;
  const float4* h1p = (const float4*)hs[1] + half * 16;
  float sum0 = 0.f, sum1 = 0.f;
  int nsteps = dir ? LA : cnt;
  for (int ti = 0; ti < nsteps; ti++) {
    int t = dir ? (LA - 1 - ti) : ti;
    const __half* gp0 = gih + ((size_t)g0 * LA + t) * 768 + j;
    const __half* gp1 = gih + ((size_t)g1 * LA + t) * 768 + j;
    float gr0 = __half2float(gp0[0]);
    float gz0 = __half2float(gp0[256]);
    float gn0 = __half2float(gp0[512]);
    float gr1 = __half2float(gp1[0]);
    float gz1 = __half2float(gp1[256]);
    float gn1 = __half2float(gp1[512]);
    float ap0 = 0.f, zp0 = 0.f, np0 = 0.f;
    float ap1 = 0.f, zp1 = 0.f, np1 = 0.f;
#pragma unroll
    for (int q = 0; q < 16; q++) {
      F4H hv0; hv0.f4 = h0p[q];
      F4H hv1; hv1.f4 = h1p[q];
#pragma unroll
      for (int u = 0; u < 4; u++) {
        ap0 = dot2acc(hv0.h[u], wr[q].h[u], ap0);
        zp0 = dot2acc(hv0.h[u], wz[q].h[u], zp0);
        np0 = dot2acc(hv0.h[u], wn[q].h[u], np0);
        ap1 = dot2acc(hv1.h[u], wr[q].h[u], ap1);
        zp1 = dot2acc(hv1.h[u], wz[q].h[u], zp1);
        np1 = dot2acc(hv1.h[u], wn[q].h[u], np1);
      }
    }
    ap0 += __shfl_xor(ap0, 1);
    zp0 += __shfl_xor(zp0, 1);
    np0 += __shfl_xor(np0, 1);
    ap1 += __shfl_xor(ap1, 1);
    zp1 += __shfl_xor(zp1, 1);
    np1 += __shfl_xor(np1, 1);
    float r0 = sigm(gr0 + br + ap0);
    float z0 = sigm(gz0 + bz + zp0);
    float n0 = tanh_fast(gn0 + bn + r0 * np0);
    float hnew0 = (1.f - z0) * n0 + z0 * hprev0;
    float r1 = sigm(gr1 + br + ap1);
    float z1 = sigm(gz1 + bz + zp1);
    float n1 = tanh_fast(gn1 + bn + r1 * np1);
    float hnew1 = (1.f - z1) * n1 + z1 * hprev1;
    __syncthreads();
    if (half == 0) {
      hs[0][j] = __float2half(hnew0);
      hs[1][j] = __float2half(hnew1);
    }
    hprev0 = hnew0;
    hprev1 = hnew1;
    if (t < cnt) { sum0 += hnew0; sum1 += hnew1; }
    __syncthreads();
  }
  if (half == 0) {
    out[(size_t)g0 * 512 + dir * 256 + j] = sum0 / (float)cnt;
    out[(size_t)g1 * 512 + dir * 256 + j] = sum1 / (float)cnt;
  }
}

extern "C" void kernel_launch(void* const* d_in, const int* in_sizes, int n_in,
                              void* d_out, int out_size, void* d_ws, size_t ws_size,
                              hipStream_t stream) {
  const float* atom_msg  = (const float*)d_in[0];
  const float* pharm_msg = (const float*)d_in[1];
  const float* hyper_msg = (const float*)d_in[2];
  const int* ac = (const int*)d_in[3];
  const int* pc = (const int*)d_in[4];
  const int* hc = (const int*)d_in[5];
  const float* p2h_Wq = (const float*)d_in[6];
  const float* p2h_bq = (const float*)d_in[7];
  const float* p2h_Wk = (const float*)d_in[8];
  const float* p2h_bk = (const float*)d_in[9];
  const float* p2h_Wv = (const float*)d_in[10];
  const float* p2h_bv = (const float*)d_in[11];
  const float* p2h_Wo = (const float*)d_in[12];
  const float* p2h_bo = (const float*)d_in[13];
  const float* a2p_Wq = (const float*)d_in[14];
  const float* a2p_bq = (const float*)d_in[15];
  const float* a2p_Wk = (const float*)d_in[16];
  const float* a2p_bk = (const float*)d_in[17];
  const float* a2p_Wv = (const float*)d_in[18];
  const float* a2p_bv = (const float*)d_in[19];
  const float* a2p_Wo = (const float*)d_in[20];
  const float* a2p_bo = (const float*)d_in[21];
  const float* Wih_f  = (const float*)d_in[22];
  const float* Whh_f  = (const float*)d_in[23];
  const float* bih_f  = (const float*)d_in[24];
  const float* bhh_f  = (const float*)d_in[25];
  const float* Wih_b  = (const float*)d_in[26];
  const float* Whh_b  = (const float*)d_in[27];
  const float* bih_b  = (const float*)d_in[28];
  const float* bhh_b  = (const float*)d_in[29];
  float* out = (float*)d_out;
  (void)in_sizes; (void)n_in; (void)out_size; (void)ws_size;

  char* wsb = (char*)d_ws;
  size_t off = 0;
  auto alloc = [&](size_t bytes) -> void* {
    void* p = wsb + off;
    off += (bytes + 255) & ~(size_t)255;
    return p;
  };
  const int MA = NB * LA, MP = NB * LP, MH = NB * LH;
  int* sa = (int*)alloc(NB * 4);
  int* sp = (int*)alloc(NB * 4);
  int* sh = (int*)alloc(NB * 4);
  __half* Wh16_f = (__half*)alloc((size_t)768 * 256 * 2);
  __half* Wh16_b = (__half*)alloc((size_t)768 * 256 * 2);
  __half* Wf16_f = (__half*)alloc((size_t)768 * 256 * 2);
  __half* Wf16_b = (__half*)alloc((size_t)768 * 256 * 2);
  __half* Wqh = (__half*)alloc((size_t)256 * 256 * 2);
  __half* Wql = (__half*)alloc((size_t)256 * 256 * 2);
  __half* Woh = (__half*)alloc((size_t)256 * 256 * 2);
  __half* Wol = (__half*)alloc((size_t)256 * 256 * 2);
  float* q_p = (float*)alloc((size_t)MP * HDIM * 4);
  float* k_h = (float*)alloc((size_t)MH * HDIM * 4);
  float* v_h = (float*)alloc((size_t)MH * HDIM * 4);
  float* ph2 = (float*)alloc((size_t)MP * HDIM * 4);
  float* q_a = (float*)alloc((size_t)MA * HDIM * 4);
  float* k_p = (float*)alloc((size_t)MP * HDIM * 4);
  float* v_p = (float*)alloc((size_t)MP * HDIM * 4);
  float* h_x = (float*)alloc((size_t)MA * HDIM * 4);
  __half* h_x16 = (__half*)alloc((size_t)MA * HDIM * 2);
  __half* gi_f = (__half*)alloc((size_t)MA * 768 * 2);
  __half* gi_b = (__half*)alloc((size_t)MA * 768 * 2);
  // hi/lo staging aliases into gi_f (dead until k_mfma_gi2): 33.3MB <= 49.9MB
  __half* Ah = gi_f;
  __half* Al = gi_f + (size_t)MA * HDIM;

  // 1. fused prep: scan + Whh cvt + Wih pack + a2p_{Wq,Wo} hi/lo pack
  {
    const int NT = 768 * 256, NP = 256 * 256;
    int blocks = (4 * NT + 2 * NP) / 256 + 1;
    k_prep<<<blocks, 256, 0, stream>>>(ac, pc, hc, sa, sp, sh,
        Whh_f, Wh16_f, Whh_b, Wh16_b, Wih_f, Wf16_f, Wih_b, Wf16_b,
        a2p_Wq, Wqh, Wql, a2p_Wo, Woh, Wol);
  }
  // 2. atom gather + hi/lo split (input to q_a MFMA)
  k_gsplit<<<(MA * 256 + 255) / 256, 256, 0, stream>>>(atom_msg, sa, ac, LA, MA, Ah, Al);

  // ---- MHA1: pharm attends to hyper ----
  k_gemm<true, false><<<dim3(MP / 64, 4), 256, 0, stream>>>(
      nullptr, pharm_msg, sp, pc, LP, p2h_Wq, p2h_bq, nullptr, q_p, nullptr, 256);
  k_gemm_kv<true><<<dim3(MH / 64, 4, 2), 256, 0, stream>>>(
      nullptr, hyper_msg, sh, hc, LH, p2h_Wk, p2h_bk, k_h, p2h_Wv, p2h_bv, v_h);
  k_attn<LP, LH, false><<<dim3(NB, NHEADS), 128, 0, stream>>>(
      q_p, k_h, v_h, pc, hc, nullptr, nullptr);
  k_gemm<false, true><<<dim3(MP / 64, 4), 256, 0, stream>>>(
      q_p, nullptr, sp, pc, LP, p2h_Wo, p2h_bo, pharm_msg, ph2, nullptr, 256);

  // ---- MHA2: atom attends to (updated) pharm ----
  k_mfma_sp<false><<<dim3(MA / 64, 4), 256, 0, stream>>>(
      Ah, Al, Wqh, Wql, a2p_bq, nullptr, nullptr, nullptr, 1, q_a, nullptr);
  k_gemm_kv<false><<<dim3(MP / 64, 4, 2), 256, 0, stream>>>(
      ph2, nullptr, nullptr, nullptr, 1, a2p_Wk, a2p_bk, k_p, a2p_Wv, a2p_bv, v_p);
  k_attn<LA, LP, true><<<dim3(NB, NHEADS), 128, 0, stream>>>(
      q_a, k_p, v_p, ac, pc, Ah, Al);
  k_mfma_sp<true><<<dim3(MA / 64, 4), 256, 0, stream>>>(
      Ah, Al, Woh, Wol, a2p_bo, atom_msg, sa, ac, LA, h_x, h_x16);

  // ---- GRU ----
  k_mfma_gi2<<<dim3(MA / 64, 24), 256, 0, stream>>>(
      h_x16, Wf16_f, Wf16_b, bih_f, bih_b, gi_f, gi_b);
  k_gru4<<<NB, 512, 0, stream>>>(h_x, Wh16_f, Wh16_b, gi_f, gi_b, bhh_f, bhh_b, ac, out);
}

// Round 16
// 782.571 us; speedup vs baseline: 1.0489x; 1.0489x over previous
//
#include <hip/hip_runtime.h>
#include <hip/hip_fp16.h>
#include <math.h>

#define NB 256
#define HDIM 256
#define NHEADS 4
#define DKH 64
#define LA 127
#define LP 23
#define LH 11

typedef _Float16 h2v __attribute__((ext_vector_type(2)));
typedef _Float16 f16x8 __attribute__((ext_vector_type(8)));
typedef float f32x4 __attribute__((ext_vector_type(4)));
union F4H { float4 f4; h2v h[4]; };

__device__ __forceinline__ float dot2acc(h2v a, h2v b, float c) {
#if __has_builtin(__builtin_amdgcn_fdot2)
  return __builtin_amdgcn_fdot2(a, b, c, false);
#else
  return c + (float)a[0] * (float)b[0] + (float)a[1] * (float)b[1];
#endif
}

__device__ __forceinline__ float sigm(float x) { return 1.0f / (1.0f + __expf(-x)); }
__device__ __forceinline__ float tanh_fast(float x) { return 2.0f / (1.0f + __expf(-2.0f * x)) - 1.0f; }

// ---------- ONE prep kernel: scan + Whh cvt x2 + Wih frag-pack x2 + proj hi/lo pack x2 ----------
__global__ void k_prep(const int* __restrict__ ac, const int* __restrict__ pc,
                       const int* __restrict__ hc, int* __restrict__ sa,
                       int* __restrict__ sp, int* __restrict__ sh,
                       const float* __restrict__ Whh_f, __half* __restrict__ Wh16_f,
                       const float* __restrict__ Whh_b, __half* __restrict__ Wh16_b,
                       const float* __restrict__ Wih_f, __half* __restrict__ Wf16_f,
                       const float* __restrict__ Wih_b, __half* __restrict__ Wf16_b,
                       const float* __restrict__ Wq, __half* __restrict__ Wqh,
                       __half* __restrict__ Wql, const float* __restrict__ Wo,
                       __half* __restrict__ Woh, __half* __restrict__ Wol) {
  const int NT = 768 * 256, NP = 256 * 256;
  if (blockIdx.x == gridDim.x - 1) {
    int t = threadIdx.x;
    if (t == 0) { int s = 0; for (int i = 0; i < NB; i++) { sa[i] = s; s += ac[i]; } }
    else if (t == 1) { int s = 0; for (int i = 0; i < NB; i++) { sp[i] = s; s += pc[i]; } }
    else if (t == 2) { int s = 0; for (int i = 0; i < NB; i++) { sh[i] = s; s += hc[i]; } }
    return;
  }
  int idx = blockIdx.x * 256 + threadIdx.x;
  if (idx < NT) { Wh16_f[idx] = __float2half(Whh_f[idx]); return; }
  idx -= NT;
  if (idx < NT) { Wh16_b[idx] = __float2half(Whh_b[idx]); return; }
  idx -= NT;
  if (idx < NT) {
    int u = idx & 7, lg = (idx >> 3) & 3, c = (idx >> 5) % 768, k0b = (idx >> 5) / 768;
    Wf16_f[idx] = __float2half(Wih_f[(size_t)c * 256 + k0b * 32 + lg * 8 + u]);
    return;
  }
  idx -= NT;
  if (idx < NT) {
    int u = idx & 7, lg = (idx >> 3) & 3, c = (idx >> 5) % 768, k0b = (idx >> 5) / 768;
    Wf16_b[idx] = __float2half(Wih_b[(size_t)c * 256 + k0b * 32 + lg * 8 + u]);
    return;
  }
  idx -= NT;
  if (idx < NP) {
    int u = idx & 7, lg = (idx >> 3) & 3, c = (idx >> 5) & 255, k0b = idx >> 13;
    float w = Wq[(size_t)(k0b * 32 + lg * 8 + u) * 256 + c];
    __half h = __float2half(w);
    Wqh[idx] = h; Wql[idx] = __float2half(w - __half2float(h));
    return;
  }
  idx -= NP;
  if (idx < NP) {
    int u = idx & 7, lg = (idx >> 3) & 3, c = (idx >> 5) & 255, k0b = idx >> 13;
    float w = Wo[(size_t)(k0b * 32 + lg * 8 + u) * 256 + c];
    __half h = __float2half(w);
    Woh[idx] = h; Wol[idx] = __float2half(w - __half2float(h));
  }
}

// ---------- generic fp32 GEMM (round-14 proven) ----------
template <bool GATHER_A, bool RES_GATHER>
__global__ __launch_bounds__(256) void k_gemm(
    const float* __restrict__ A, const float* __restrict__ msg,
    const int* __restrict__ starts, const int* __restrict__ counts, int L,
    const float* __restrict__ W, const float* __restrict__ bias,
    const float* __restrict__ resmsg, float* __restrict__ C,
    __half* __restrict__ Ch, int N) {
  const int K = HDIM;
  __shared__ float As[16][76];
  __shared__ float Ws[16][72];
  int tid = threadIdx.x;
  int row0 = blockIdx.x * 64, col0 = blockIdx.y * 64;
  int arow = row0 + (tid >> 2);
  const float* asrc;
  if constexpr (GATHER_A) {
    int b = arow / L, t = arow - b * L;
    asrc = (t < counts[b]) ? (msg + (size_t)(starts[b] + t) * K) : nullptr;
  } else {
    asrc = A + (size_t)arow * K;
  }
  int ak = (tid & 3) * 4;
  int wk = tid >> 4, wn = (tid & 15) * 4;
  int ty = tid >> 4, tx = tid & 15;
  float acc[4][4] = {};
  for (int k0 = 0; k0 < K; k0 += 16) {
    float4 av = make_float4(0.f, 0.f, 0.f, 0.f);
    if (asrc) av = *(const float4*)(asrc + k0 + ak);
    float4 wv = *(const float4*)(W + (size_t)(k0 + wk) * N + col0 + wn);
    __syncthreads();
    int m = tid >> 2;
    As[ak + 0][m] = av.x; As[ak + 1][m] = av.y;
    As[ak + 2][m] = av.z; As[ak + 3][m] = av.w;
    *(float4*)&Ws[wk][wn] = wv;
    __syncthreads();
#pragma unroll
    for (int kk = 0; kk < 16; kk++) {
      float4 a = *(const float4*)&As[kk][ty * 4];
      float4 b = *(const float4*)&Ws[kk][tx * 4];
      acc[0][0] += a.x * b.x; acc[0][1] += a.x * b.y; acc[0][2] += a.x * b.z; acc[0][3] += a.x * b.w;
      acc[1][0] += a.y * b.x; acc[1][1] += a.y * b.y; acc[1][2] += a.y * b.z; acc[1][3] += a.y * b.w;
      acc[2][0] += a.z * b.x; acc[2][1] += a.z * b.y; acc[2][2] += a.z * b.z; acc[2][3] += a.z * b.w;
      acc[3][0] += a.w * b.x; acc[3][1] += a.w * b.y; acc[3][2] += a.w * b.z; acc[3][3] += a.w * b.w;
    }
  }
  float4 bv = *(const float4*)(bias + col0 + tx * 4);
#pragma unroll
  for (int i = 0; i < 4; i++) {
    int r = row0 + ty * 4 + i;
    float o0 = acc[i][0] + bv.x, o1 = acc[i][1] + bv.y,
          o2 = acc[i][2] + bv.z, o3 = acc[i][3] + bv.w;
    if constexpr (RES_GATHER) {
      int b = r / L, t = r - b * L;
      if (t < counts[b]) {
        float4 rv = *(const float4*)(resmsg + (size_t)(starts[b] + t) * K + col0 + tx * 4);
        o0 += rv.x; o1 += rv.y; o2 += rv.z; o3 += rv.w;
      }
    }
    size_t o = (size_t)r * N + col0 + tx * 4;
    *(float4*)(C + o) = make_float4(o0, o1, o2, o3);
    if (Ch) {
      Ch[o] = __float2half(o0); Ch[o + 1] = __float2half(o1);
      Ch[o + 2] = __float2half(o2); Ch[o + 3] = __float2half(o3);
    }
  }
}

// ---------- dual-output fp32 GEMM (blockIdx.z selects {W,bias,C}) ----------
template <bool GATHER_A>
__global__ __launch_bounds__(256) void k_gemm_kv(
    const float* __restrict__ A, const float* __restrict__ msg,
    const int* __restrict__ starts, const int* __restrict__ counts, int L,
    const float* __restrict__ W0, const float* __restrict__ b0, float* __restrict__ C0,
    const float* __restrict__ W1, const float* __restrict__ b1, float* __restrict__ C1) {
  const int K = HDIM, N = HDIM;
  const float* W = blockIdx.z ? W1 : W0;
  const float* bias = blockIdx.z ? b1 : b0;
  float* C = blockIdx.z ? C1 : C0;
  __shared__ float As[16][76];
  __shared__ float Ws[16][72];
  int tid = threadIdx.x;
  int row0 = blockIdx.x * 64, col0 = blockIdx.y * 64;
  int arow = row0 + (tid >> 2);
  const float* asrc;
  if constexpr (GATHER_A) {
    int b = arow / L, t = arow - b * L;
    asrc = (t < counts[b]) ? (msg + (size_t)(starts[b] + t) * K) : nullptr;
  } else {
    asrc = A + (size_t)arow * K;
  }
  int ak = (tid & 3) * 4;
  int wk = tid >> 4, wn = (tid & 15) * 4;
  int ty = tid >> 4, tx = tid & 15;
  float acc[4][4] = {};
  for (int k0 = 0; k0 < K; k0 += 16) {
    float4 av = make_float4(0.f, 0.f, 0.f, 0.f);
    if (asrc) av = *(const float4*)(asrc + k0 + ak);
    float4 wv = *(const float4*)(W + (size_t)(k0 + wk) * N + col0 + wn);
    __syncthreads();
    int m = tid >> 2;
    As[ak + 0][m] = av.x; As[ak + 1][m] = av.y;
    As[ak + 2][m] = av.z; As[ak + 3][m] = av.w;
    *(float4*)&Ws[wk][wn] = wv;
    __syncthreads();
#pragma unroll
    for (int kk = 0; kk < 16; kk++) {
      float4 a = *(const float4*)&As[kk][ty * 4];
      float4 b = *(const float4*)&Ws[kk][tx * 4];
      acc[0][0] += a.x * b.x; acc[0][1] += a.x * b.y; acc[0][2] += a.x * b.z; acc[0][3] += a.x * b.w;
      acc[1][0] += a.y * b.x; acc[1][1] += a.y * b.y; acc[1][2] += a.y * b.z; acc[1][3] += a.y * b.w;
      acc[2][0] += a.z * b.x; acc[2][1] += a.z * b.y; acc[2][2] += a.z * b.z; acc[2][3] += a.z * b.w;
      acc[3][0] += a.w * b.x; acc[3][1] += a.w * b.y; acc[3][2] += a.w * b.z; acc[3][3] += a.w * b.w;
    }
  }
  float4 bv = *(const float4*)(bias + col0 + tx * 4);
#pragma unroll
  for (int i = 0; i < 4; i++) {
    int r = row0 + ty * 4 + i;
    size_t o = (size_t)r * N + col0 + tx * 4;
    *(float4*)(C + o) = make_float4(acc[i][0] + bv.x, acc[i][1] + bv.y,
                                    acc[i][2] + bv.z, acc[i][3] + bv.w);
  }
}

// ---------- split-fp16 MFMA GEMM, fp32 input, IN-KERNEL hi/lo split ----------
// acc = ah@bh + al@bh + ah@bl (round-11/15-proven numerics, ~1e-5 error).
// No staging dispatch: A read as fp32 (same traffic as the fp32 GEMM it
// replaces), split in registers. W hi/lo frag-packed by k_prep.
template <bool GATHER, bool RES>
__global__ __launch_bounds__(256) void k_mfma_sp32(
    const float* __restrict__ A, const float* __restrict__ msg,
    const int* __restrict__ starts, const int* __restrict__ counts, int L,
    const __half* __restrict__ Whi, const __half* __restrict__ Wlo,
    const float* __restrict__ bias, const float* __restrict__ resmsg,
    float* __restrict__ Out, __half* __restrict__ Ch) {
  int w = threadIdx.x >> 6, l = threadIdx.x & 63;
  int row0 = blockIdx.x * 64 + w * 16;
  int col0 = blockIdx.y * 64;
  int lr = l & 15, lg = l >> 4;
  int arow = row0 + lr;
  const float* asrc;
  if constexpr (GATHER) {
    int b = arow / L, t = arow - b * L;
    asrc = (t < counts[b]) ? (msg + (size_t)(starts[b] + t) * 256) : nullptr;
  } else {
    asrc = A + (size_t)arow * 256;
  }
  f32x4 acc[4] = {};
#pragma unroll
  for (int k0b = 0; k0b < 8; k0b++) {
    f16x8 ah, al;
    if (asrc) {
      float av[8];
      *(float4*)&av[0] = *(const float4*)(asrc + k0b * 32 + lg * 8);
      *(float4*)&av[4] = *(const float4*)(asrc + k0b * 32 + lg * 8 + 4);
#pragma unroll
      for (int u = 0; u < 8; u++) {
        _Float16 h = (_Float16)av[u];
        ah[u] = h;
        al[u] = (_Float16)(av[u] - (float)h);
      }
    } else {
#pragma unroll
      for (int u = 0; u < 8; u++) { ah[u] = (_Float16)0.f; al[u] = (_Float16)0.f; }
    }
#pragma unroll
    for (int nt = 0; nt < 4; nt++) {
      int c = col0 + nt * 16 + lr;
      size_t wi = ((size_t)(k0b * 256 + c) * 4 + lg) * 8;
      f16x8 bh = *(const f16x8*)(Whi + wi);
      f16x8 bl = *(const f16x8*)(Wlo + wi);
      acc[nt] = __builtin_amdgcn_mfma_f32_16x16x32_f16(ah, bh, acc[nt], 0, 0, 0);
      acc[nt] = __builtin_amdgcn_mfma_f32_16x16x32_f16(al, bh, acc[nt], 0, 0, 0);
      acc[nt] = __builtin_amdgcn_mfma_f32_16x16x32_f16(ah, bl, acc[nt], 0, 0, 0);
    }
  }
#pragma unroll
  for (int nt = 0; nt < 4; nt++) {
    int c = col0 + nt * 16 + lr;
    float bv = bias[c];
#pragma unroll
    for (int r = 0; r < 4; r++) {
      int row = row0 + lg * 4 + r;
      float o = acc[nt][r] + bv;
      if constexpr (RES) {
        int b = row / L, t = row - b * L;
        if (t < counts[b]) o += resmsg[(size_t)(starts[b] + t) * 256 + c];
      }
      size_t oidx = (size_t)row * 256 + c;
      Out[oidx] = o;
      if (Ch) Ch[oidx] = __float2half(o);
    }
  }
}

// ---------- fused dual MFMA fp16 GEMM for gi ----------
__global__ __launch_bounds__(256) void k_mfma_gi2(
    const __half* __restrict__ A16,
    const __half* __restrict__ Wf_f, const __half* __restrict__ Wf_b,
    const float* __restrict__ bias_f, const float* __restrict__ bias_b,
    __half* __restrict__ Out_f, __half* __restrict__ Out_b) {
  const int N = 768;
  int y = blockIdx.y;
  const __half* Wf = y < 12 ? Wf_f : Wf_b;
  const float* bias = y < 12 ? bias_f : bias_b;
  __half* Out = y < 12 ? Out_f : Out_b;
  int col0 = (y < 12 ? y : y - 12) * 64;
  int w = threadIdx.x >> 6, l = threadIdx.x & 63;
  int row0 = blockIdx.x * 64 + w * 16;
  int lr = l & 15, lg = l >> 4;
  f32x4 acc[4] = {};
  const __half* arow = A16 + (size_t)(row0 + lr) * 256 + lg * 8;
#pragma unroll
  for (int k0b = 0; k0b < 8; k0b++) {
    f16x8 a = *(const f16x8*)(arow + k0b * 32);
#pragma unroll
    for (int nt = 0; nt < 4; nt++) {
      int c = col0 + nt * 16 + lr;
      f16x8 b = *(const f16x8*)(Wf + ((size_t)(k0b * N + c) * 4 + lg) * 8);
      acc[nt] = __builtin_amdgcn_mfma_f32_16x16x32_f16(a, b, acc[nt], 0, 0, 0);
    }
  }
#pragma unroll
  for (int nt = 0; nt < 4; nt++) {
    int c = col0 + nt * 16 + lr;
    float bv = bias[c];
#pragma unroll
    for (int r = 0; r < 4; r++) {
      int row = row0 + lg * 4 + r;
      Out[(size_t)row * N + c] = __float2half(acc[nt][r] + bv);
    }
  }
}

// ---------- attention (round-14 proven original) ----------
template <int LQ, int LK>
__global__ __launch_bounds__(128) void k_attn(
    float* __restrict__ q, const float* __restrict__ kbuf,
    const float* __restrict__ vbuf, const int* __restrict__ cq,
    const int* __restrict__ ck) {
  __shared__ float qs[LQ][65];
  __shared__ float ks[LK][65];
  __shared__ float vs[LK][65];
  int b = blockIdx.x, head = blockIdx.y;
  int tid = threadIdx.x;
  for (int idx = tid; idx < LQ * 16; idx += 128) {
    int i = idx >> 4, c = (idx & 15) * 4;
    float4 v = *(const float4*)(q + (size_t)(b * LQ + i) * HDIM + head * DKH + c);
    qs[i][c] = v.x; qs[i][c + 1] = v.y; qs[i][c + 2] = v.z; qs[i][c + 3] = v.w;
  }
  for (int idx = tid; idx < LK * 16; idx += 128) {
    int i = idx >> 4, c = (idx & 15) * 4;
    float4 v = *(const float4*)(kbuf + (size_t)(b * LK + i) * HDIM + head * DKH + c);
    ks[i][c] = v.x; ks[i][c + 1] = v.y; ks[i][c + 2] = v.z; ks[i][c + 3] = v.w;
    float4 w = *(const float4*)(vbuf + (size_t)(b * LK + i) * HDIM + head * DKH + c);
    vs[i][c] = w.x; vs[i][c + 1] = w.y; vs[i][c + 2] = w.z; vs[i][c + 3] = w.w;
  }
  __syncthreads();
  int nq = cq[b], nk = ck[b];
  for (int i = tid; i < LQ; i += 128) {
    float s[LK];
    float mx = -INFINITY;
    bool qv = i < nq;
#pragma unroll
    for (int k = 0; k < LK; k++) {
      float d = -1e9f;
      if (qv && k < nk) {
        float acc = 0.f;
        for (int c = 0; c < DKH; c++) acc += qs[i][c] * ks[k][c];
        d = acc * 0.125f;
      }
      s[k] = d;
      mx = fmaxf(mx, d);
    }
    float den = 0.f;
#pragma unroll
    for (int k = 0; k < LK; k++) { s[k] = expf(s[k] - mx); den += s[k]; }
    float inv = 1.0f / den;
    for (int c = 0; c < DKH; c++) {
      float acc = 0.f;
#pragma unroll
      for (int k = 0; k < LK; k++) acc += s[k] * vs[k][c];
      q[(size_t)(b * LQ + i) * HDIM + head * DKH + c] = acc * inv;
    }
  }
}

// ---------- h0 = max over the 127 positions (standalone, round-14 proven) ----------
__global__ void k_rowmax(const float* __restrict__ h, float* __restrict__ h0) {
  int b = blockIdx.x, j = threadIdx.x;
  float m = -INFINITY;
  for (int t = 0; t < LA; t++) m = fmaxf(m, h[((size_t)b * LA + t) * HDIM + j]);
  h0[b * HDIM + j] = m;
}

// ---------- GRU v4 (round-14 proven exact) ----------
__global__ __launch_bounds__(512, 2) void k_gru4(
    const float* __restrict__ h0, const __half* __restrict__ Wh_f,
    const __half* __restrict__ Wh_b, const __half* __restrict__ gi_f,
    const __half* __restrict__ gi_b, const float* __restrict__ bhh_f,
    const float* __restrict__ bhh_b, const int* __restrict__ ac,
    float* __restrict__ out) {
  int bid = blockIdx.x;
  int dir = bid & 1, pair = bid >> 1;
  int g0 = pair, g1 = pair + 128;
  int tid = threadIdx.x;
  int j = tid >> 1, half = tid & 1;
  const __half* W = dir ? Wh_b : Wh_f;
  const __half* gih = dir ? gi_b : gi_f;
  const float* bhh = dir ? bhh_b : bhh_f;

  F4H wr[16], wz[16], wn[16];
  {
    const float4* Wr4 = (const float4*)(W + (size_t)j * 256 + half * 128);
    const float4* Wz4 = (const float4*)(W + (size_t)(256 + j) * 256 + half * 128);
    const float4* Wn4 = (const float4*)(W + (size_t)(512 + j) * 256 + half * 128);
#pragma unroll
    for (int p = 0; p < 16; p++) wr[p].f4 = Wr4[p];
#pragma unroll
    for (int p = 0; p < 16; p++) wz[p].f4 = Wz4[p];
#pragma unroll
    for (int p = 0; p < 16; p++) wn[p].f4 = Wn4[p];
  }
  float br = bhh[j], bz = bhh[256 + j], bn = bhh[512 + j];
  int cnt = ac[g0];

  __shared__ __align__(16) __half hs[2][HDIM];
  float hprev0 = h0[(size_t)g0 * HDIM + j];
  float hprev1 = h0[(size_t)g1 * HDIM + j];
  if (half == 0) {
    hs[0][j] = __float2half(hprev0);
    hs[1][j] = __float2half(hprev1);
  }
  __syncthreads();

  const float4* h0p = (const float4*)hs[0] + half * 16;
  const float4* h1p = (const float4*)hs[1] + half * 16;
  float sum0 = 0.f, sum1 = 0.f;
  int nsteps = dir ? LA : cnt;
  for (int ti = 0; ti < nsteps; ti++) {
    int t = dir ? (LA - 1 - ti) : ti;
    const __half* gp0 = gih + ((size_t)g0 * LA + t) * 768 + j;
    const __half* gp1 = gih + ((size_t)g1 * LA + t) * 768 + j;
    float gr0 = __half2float(gp0[0]);
    float gz0 = __half2float(gp0[256]);
    float gn0 = __half2float(gp0[512]);
    float gr1 = __half2float(gp1[0]);
    float gz1 = __half2float(gp1[256]);
    float gn1 = __half2float(gp1[512]);
    float ap0 = 0.f, zp0 = 0.f, np0 = 0.f;
    float ap1 = 0.f, zp1 = 0.f, np1 = 0.f;
#pragma unroll
    for (int q = 0; q < 16; q++) {
      F4H hv0; hv0.f4 = h0p[q];
      F4H hv1; hv1.f4 = h1p[q];
#pragma unroll
      for (int u = 0; u < 4; u++) {
        ap0 = dot2acc(hv0.h[u], wr[q].h[u], ap0);
        zp0 = dot2acc(hv0.h[u], wz[q].h[u], zp0);
        np0 = dot2acc(hv0.h[u], wn[q].h[u], np0);
        ap1 = dot2acc(hv1.h[u], wr[q].h[u], ap1);
        zp1 = dot2acc(hv1.h[u], wz[q].h[u], zp1);
        np1 = dot2acc(hv1.h[u], wn[q].h[u], np1);
      }
    }
    ap0 += __shfl_xor(ap0, 1);
    zp0 += __shfl_xor(zp0, 1);
    np0 += __shfl_xor(np0, 1);
    ap1 += __shfl_xor(ap1, 1);
    zp1 += __shfl_xor(zp1, 1);
    np1 += __shfl_xor(np1, 1);
    float r0 = sigm(gr0 + br + ap0);
    float z0 = sigm(gz0 + bz + zp0);
    float n0 = tanh_fast(gn0 + bn + r0 * np0);
    float hnew0 = (1.f - z0) * n0 + z0 * hprev0;
    float r1 = sigm(gr1 + br + ap1);
    float z1 = sigm(gz1 + bz + zp1);
    float n1 = tanh_fast(gn1 + bn + r1 * np1);
    float hnew1 = (1.f - z1) * n1 + z1 * hprev1;
    __syncthreads();
    if (half == 0) {
      hs[0][j] = __float2half(hnew0);
      hs[1][j] = __float2half(hnew1);
    }
    hprev0 = hnew0;
    hprev1 = hnew1;
    if (t < cnt) { sum0 += hnew0; sum1 += hnew1; }
    __syncthreads();
  }
  if (half == 0) {
    out[(size_t)g0 * 512 + dir * 256 + j] = sum0 / (float)cnt;
    out[(size_t)g1 * 512 + dir * 256 + j] = sum1 / (float)cnt;
  }
}

extern "C" void kernel_launch(void* const* d_in, const int* in_sizes, int n_in,
                              void* d_out, int out_size, void* d_ws, size_t ws_size,
                              hipStream_t stream) {
  const float* atom_msg  = (const float*)d_in[0];
  const float* pharm_msg = (const float*)d_in[1];
  const float* hyper_msg = (const float*)d_in[2];
  const int* ac = (const int*)d_in[3];
  const int* pc = (const int*)d_in[4];
  const int* hc = (const int*)d_in[5];
  const float* p2h_Wq = (const float*)d_in[6];
  const float* p2h_bq = (const float*)d_in[7];
  const float* p2h_Wk = (const float*)d_in[8];
  const float* p2h_bk = (const float*)d_in[9];
  const float* p2h_Wv = (const float*)d_in[10];
  const float* p2h_bv = (const float*)d_in[11];
  const float* p2h_Wo = (const float*)d_in[12];
  const float* p2h_bo = (const float*)d_in[13];
  const float* a2p_Wq = (const float*)d_in[14];
  const float* a2p_bq = (const float*)d_in[15];
  const float* a2p_Wk = (const float*)d_in[16];
  const float* a2p_bk = (const float*)d_in[17];
  const float* a2p_Wv = (const float*)d_in[18];
  const float* a2p_bv = (const float*)d_in[19];
  const float* a2p_Wo = (const float*)d_in[20];
  const float* a2p_bo = (const float*)d_in[21];
  const float* Wih_f  = (const float*)d_in[22];
  const float* Whh_f  = (const float*)d_in[23];
  const float* bih_f  = (const float*)d_in[24];
  const float* bhh_f  = (const float*)d_in[25];
  const float* Wih_b  = (const float*)d_in[26];
  const float* Whh_b  = (const float*)d_in[27];
  const float* bih_b  = (const float*)d_in[28];
  const float* bhh_b  = (const float*)d_in[29];
  float* out = (float*)d_out;
  (void)in_sizes; (void)n_in; (void)out_size; (void)ws_size;

  char* wsb = (char*)d_ws;
  size_t off = 0;
  auto alloc = [&](size_t bytes) -> void* {
    void* p = wsb + off;
    off += (bytes + 255) & ~(size_t)255;
    return p;
  };
  const int MA = NB * LA, MP = NB * LP, MH = NB * LH;
  int* sa = (int*)alloc(NB * 4);
  int* sp = (int*)alloc(NB * 4);
  int* sh = (int*)alloc(NB * 4);
  __half* Wh16_f = (__half*)alloc((size_t)768 * 256 * 2);
  __half* Wh16_b = (__half*)alloc((size_t)768 * 256 * 2);
  __half* Wf16_f = (__half*)alloc((size_t)768 * 256 * 2);
  __half* Wf16_b = (__half*)alloc((size_t)768 * 256 * 2);
  __half* Wqh = (__half*)alloc((size_t)256 * 256 * 2);
  __half* Wql = (__half*)alloc((size_t)256 * 256 * 2);
  __half* Woh = (__half*)alloc((size_t)256 * 256 * 2);
  __half* Wol = (__half*)alloc((size_t)256 * 256 * 2);
  float* q_p = (float*)alloc((size_t)MP * HDIM * 4);
  float* k_h = (float*)alloc((size_t)MH * HDIM * 4);
  float* v_h = (float*)alloc((size_t)MH * HDIM * 4);
  float* ph2 = (float*)alloc((size_t)MP * HDIM * 4);
  float* q_a = (float*)alloc((size_t)MA * HDIM * 4);
  float* k_p = (float*)alloc((size_t)MP * HDIM * 4);
  float* v_p = (float*)alloc((size_t)MP * HDIM * 4);
  float* h_x = (float*)alloc((size_t)MA * HDIM * 4);
  __half* h_x16 = (__half*)alloc((size_t)MA * HDIM * 2);
  float* h0  = (float*)alloc((size_t)NB * HDIM * 4);
  __half* gi_f = (__half*)alloc((size_t)MA * 768 * 2);
  __half* gi_b = (__half*)alloc((size_t)MA * 768 * 2);

  // 1. fused prep: scan + Whh cvt + Wih pack + a2p_{Wq,Wo} hi/lo pack
  {
    const int NT = 768 * 256, NP = 256 * 256;
    int blocks = (4 * NT + 2 * NP) / 256 + 1;
    k_prep<<<blocks, 256, 0, stream>>>(ac, pc, hc, sa, sp, sh,
        Whh_f, Wh16_f, Whh_b, Wh16_b, Wih_f, Wf16_f, Wih_b, Wf16_b,
        a2p_Wq, Wqh, Wql, a2p_Wo, Woh, Wol);
  }

  // ---- MHA1: pharm attends to hyper ----
  k_gemm<true, false><<<dim3(MP / 64, 4), 256, 0, stream>>>(
      nullptr, pharm_msg, sp, pc, LP, p2h_Wq, p2h_bq, nullptr, q_p, nullptr, 256);
  k_gemm_kv<true><<<dim3(MH / 64, 4, 2), 256, 0, stream>>>(
      nullptr, hyper_msg, sh, hc, LH, p2h_Wk, p2h_bk, k_h, p2h_Wv, p2h_bv, v_h);
  k_attn<LP, LH><<<dim3(NB, NHEADS), 128, 0, stream>>>(q_p, k_h, v_h, pc, hc);
  k_gemm<false, true><<<dim3(MP / 64, 4), 256, 0, stream>>>(
      q_p, nullptr, sp, pc, LP, p2h_Wo, p2h_bo, pharm_msg, ph2, nullptr, 256);

  // ---- MHA2: atom attends to (updated) pharm ----
  k_mfma_sp32<true, false><<<dim3(MA / 64, 4), 256, 0, stream>>>(
      nullptr, atom_msg, sa, ac, LA, Wqh, Wql, a2p_bq, nullptr, q_a, nullptr);
  k_gemm_kv<false><<<dim3(MP / 64, 4, 2), 256, 0, stream>>>(
      ph2, nullptr, nullptr, nullptr, 1, a2p_Wk, a2p_bk, k_p, a2p_Wv, a2p_bv, v_p);
  k_attn<LA, LP><<<dim3(NB, NHEADS), 128, 0, stream>>>(q_a, k_p, v_p, ac, pc);
  k_mfma_sp32<false, true><<<dim3(MA / 64, 4), 256, 0, stream>>>(
      q_a, nullptr, sa, ac, LA, Woh, Wol, a2p_bo, atom_msg, h_x, h_x16);

  // ---- GRU ----
  k_rowmax<<<NB, 256, 0, stream>>>(h_x, h0);
  k_mfma_gi2<<<dim3(MA / 64, 24), 256, 0, stream>>>(
      h_x16, Wf16_f, Wf16_b, bih_f, bih_b, gi_f, gi_b);
  k_gru4<<<NB, 512, 0, stream>>>(h0, Wh16_f, Wh16_b, gi_f, gi_b, bhh_f, bhh_b, ac, out);
}

// Round 17
// 737.037 us; speedup vs baseline: 1.1137x; 1.0618x over previous
//
#include <hip/hip_runtime.h>
#include <hip/hip_fp16.h>
#include <math.h>

#define NB 256
#define HDIM 256
#define NHEADS 4
#define DKH 64
#define LA 127
#define LP 23
#define LH 11

typedef _Float16 h2v __attribute__((ext_vector_type(2)));
typedef _Float16 f16x8 __attribute__((ext_vector_type(8)));
typedef float f32x4 __attribute__((ext_vector_type(4)));
union F4H { float4 f4; h2v h[4]; };

__device__ __forceinline__ float dot2acc(h2v a, h2v b, float c) {
#if __has_builtin(__builtin_amdgcn_fdot2)
  return __builtin_amdgcn_fdot2(a, b, c, false);
#else
  return c + (float)a[0] * (float)b[0] + (float)a[1] * (float)b[1];
#endif
}

__device__ __forceinline__ float sigm(float x) { return 1.0f / (1.0f + __expf(-x)); }
__device__ __forceinline__ float tanh_fast(float x) { return 2.0f / (1.0f + __expf(-2.0f * x)) - 1.0f; }

// ---------- ONE prep kernel: scan + Whh cvt x2 + Wih frag-pack x2 ----------
__global__ void k_prep(const int* __restrict__ ac, const int* __restrict__ pc,
                       const int* __restrict__ hc, int* __restrict__ sa,
                       int* __restrict__ sp, int* __restrict__ sh,
                       const float* __restrict__ Whh_f, __half* __restrict__ Wh16_f,
                       const float* __restrict__ Whh_b, __half* __restrict__ Wh16_b,
                       const float* __restrict__ Wih_f, __half* __restrict__ Wf16_f,
                       const float* __restrict__ Wih_b, __half* __restrict__ Wf16_b) {
  const int NT = 768 * 256;
  if (blockIdx.x == gridDim.x - 1) {
    int t = threadIdx.x;
    if (t == 0) { int s = 0; for (int i = 0; i < NB; i++) { sa[i] = s; s += ac[i]; } }
    else if (t == 1) { int s = 0; for (int i = 0; i < NB; i++) { sp[i] = s; s += pc[i]; } }
    else if (t == 2) { int s = 0; for (int i = 0; i < NB; i++) { sh[i] = s; s += hc[i]; } }
    return;
  }
  int idx = blockIdx.x * 256 + threadIdx.x;
  if (idx < NT) { Wh16_f[idx] = __float2half(Whh_f[idx]); return; }
  idx -= NT;
  if (idx < NT) { Wh16_b[idx] = __float2half(Whh_b[idx]); return; }
  idx -= NT;
  if (idx < NT) {
    int u = idx & 7, lg = (idx >> 3) & 3, c = (idx >> 5) % 768, k0b = (idx >> 5) / 768;
    Wf16_f[idx] = __float2half(Wih_f[(size_t)c * 256 + k0b * 32 + lg * 8 + u]);
    return;
  }
  idx -= NT;
  if (idx < NT) {
    int u = idx & 7, lg = (idx >> 3) & 3, c = (idx >> 5) % 768, k0b = (idx >> 5) / 768;
    Wf16_b[idx] = __float2half(Wih_b[(size_t)c * 256 + k0b * 32 + lg * 8 + u]);
    return;
  }
}

// ---------- generic fp32 GEMM (round-14 proven; Ch!=null adds fp16 mirror) ----------
template <bool GATHER_A, bool RES_GATHER>
__global__ __launch_bounds__(256) void k_gemm(
    const float* __restrict__ A, const float* __restrict__ msg,
    const int* __restrict__ starts, const int* __restrict__ counts, int L,
    const float* __restrict__ W, const float* __restrict__ bias,
    const float* __restrict__ resmsg, float* __restrict__ C,
    __half* __restrict__ Ch, int N) {
  const int K = HDIM;
  __shared__ float As[16][76];
  __shared__ float Ws[16][72];
  int tid = threadIdx.x;
  int row0 = blockIdx.x * 64, col0 = blockIdx.y * 64;
  int arow = row0 + (tid >> 2);
  const float* asrc;
  if constexpr (GATHER_A) {
    int b = arow / L, t = arow - b * L;
    asrc = (t < counts[b]) ? (msg + (size_t)(starts[b] + t) * K) : nullptr;
  } else {
    asrc = A + (size_t)arow * K;
  }
  int ak = (tid & 3) * 4;
  int wk = tid >> 4, wn = (tid & 15) * 4;
  int ty = tid >> 4, tx = tid & 15;
  float acc[4][4] = {};
  for (int k0 = 0; k0 < K; k0 += 16) {
    float4 av = make_float4(0.f, 0.f, 0.f, 0.f);
    if (asrc) av = *(const float4*)(asrc + k0 + ak);
    float4 wv = *(const float4*)(W + (size_t)(k0 + wk) * N + col0 + wn);
    __syncthreads();
    int m = tid >> 2;
    As[ak + 0][m] = av.x; As[ak + 1][m] = av.y;
    As[ak + 2][m] = av.z; As[ak + 3][m] = av.w;
    *(float4*)&Ws[wk][wn] = wv;
    __syncthreads();
#pragma unroll
    for (int kk = 0; kk < 16; kk++) {
      float4 a = *(const float4*)&As[kk][ty * 4];
      float4 b = *(const float4*)&Ws[kk][tx * 4];
      acc[0][0] += a.x * b.x; acc[0][1] += a.x * b.y; acc[0][2] += a.x * b.z; acc[0][3] += a.x * b.w;
      acc[1][0] += a.y * b.x; acc[1][1] += a.y * b.y; acc[1][2] += a.y * b.z; acc[1][3] += a.y * b.w;
      acc[2][0] += a.z * b.x; acc[2][1] += a.z * b.y; acc[2][2] += a.z * b.z; acc[2][3] += a.z * b.w;
      acc[3][0] += a.w * b.x; acc[3][1] += a.w * b.y; acc[3][2] += a.w * b.z; acc[3][3] += a.w * b.w;
    }
  }
  float4 bv = *(const float4*)(bias + col0 + tx * 4);
#pragma unroll
  for (int i = 0; i < 4; i++) {
    int r = row0 + ty * 4 + i;
    float o0 = acc[i][0] + bv.x, o1 = acc[i][1] + bv.y,
          o2 = acc[i][2] + bv.z, o3 = acc[i][3] + bv.w;
    if constexpr (RES_GATHER) {
      int b = r / L, t = r - b * L;
      if (t < counts[b]) {
        float4 rv = *(const float4*)(resmsg + (size_t)(starts[b] + t) * K + col0 + tx * 4);
        o0 += rv.x; o1 += rv.y; o2 += rv.z; o3 += rv.w;
      }
    }
    size_t o = (size_t)r * N + col0 + tx * 4;
    *(float4*)(C + o) = make_float4(o0, o1, o2, o3);
    if (Ch) {
      Ch[o] = __float2half(o0); Ch[o + 1] = __float2half(o1);
      Ch[o + 2] = __float2half(o2); Ch[o + 3] = __float2half(o3);
    }
  }
}

// ---------- triple-output fp32 GEMM: blockIdx.z selects {src,W,bias,C} set ----------
// One dispatch replaces the q/k/v projection trio. Math identical to k_gemm.
__global__ __launch_bounds__(256) void k_gemm_qkv(
    const float* A0, const int* st0, const int* ct0, int L0, int g0, int nr0,
    const float* W0, const float* b0, float* C0,
    const float* A1, const int* st1, const int* ct1, int L1, int g1, int nr1,
    const float* W1, const float* b1, float* C1,
    const float* A2, const int* st2, const int* ct2, int L2, int g2, int nr2,
    const float* W2, const float* b2, float* C2) {
  const int K = HDIM, N = HDIM;
  int z = blockIdx.z;
  const float* A; const int* starts; const int* counts; int L, gat, nrows;
  const float* W; const float* bias; float* C;
  if (z == 0)      { A = A0; starts = st0; counts = ct0; L = L0; gat = g0; nrows = nr0; W = W0; bias = b0; C = C0; }
  else if (z == 1) { A = A1; starts = st1; counts = ct1; L = L1; gat = g1; nrows = nr1; W = W1; bias = b1; C = C1; }
  else             { A = A2; starts = st2; counts = ct2; L = L2; gat = g2; nrows = nr2; W = W2; bias = b2; C = C2; }
  int row0 = blockIdx.x * 64, col0 = blockIdx.y * 64;
  if (row0 >= nrows) return;
  __shared__ float As[16][76];
  __shared__ float Ws[16][72];
  int tid = threadIdx.x;
  int arow = row0 + (tid >> 2);
  const float* asrc;
  if (gat) {
    int b = arow / L, t = arow - b * L;
    asrc = (t < counts[b]) ? (A + (size_t)(starts[b] + t) * K) : nullptr;
  } else {
    asrc = A + (size_t)arow * K;
  }
  int ak = (tid & 3) * 4;
  int wk = tid >> 4, wn = (tid & 15) * 4;
  int ty = tid >> 4, tx = tid & 15;
  float acc[4][4] = {};
  for (int k0 = 0; k0 < K; k0 += 16) {
    float4 av = make_float4(0.f, 0.f, 0.f, 0.f);
    if (asrc) av = *(const float4*)(asrc + k0 + ak);
    float4 wv = *(const float4*)(W + (size_t)(k0 + wk) * N + col0 + wn);
    __syncthreads();
    int m = tid >> 2;
    As[ak + 0][m] = av.x; As[ak + 1][m] = av.y;
    As[ak + 2][m] = av.z; As[ak + 3][m] = av.w;
    *(float4*)&Ws[wk][wn] = wv;
    __syncthreads();
#pragma unroll
    for (int kk = 0; kk < 16; kk++) {
      float4 a = *(const float4*)&As[kk][ty * 4];
      float4 b = *(const float4*)&Ws[kk][tx * 4];
      acc[0][0] += a.x * b.x; acc[0][1] += a.x * b.y; acc[0][2] += a.x * b.z; acc[0][3] += a.x * b.w;
      acc[1][0] += a.y * b.x; acc[1][1] += a.y * b.y; acc[1][2] += a.y * b.z; acc[1][3] += a.y * b.w;
      acc[2][0] += a.z * b.x; acc[2][1] += a.z * b.y; acc[2][2] += a.z * b.z; acc[2][3] += a.z * b.w;
      acc[3][0] += a.w * b.x; acc[3][1] += a.w * b.y; acc[3][2] += a.w * b.z; acc[3][3] += a.w * b.w;
    }
  }
  float4 bv = *(const float4*)(bias + col0 + tx * 4);
#pragma unroll
  for (int i = 0; i < 4; i++) {
    int r = row0 + ty * 4 + i;
    size_t o = (size_t)r * N + col0 + tx * 4;
    *(float4*)(C + o) = make_float4(acc[i][0] + bv.x, acc[i][1] + bv.y,
                                    acc[i][2] + bv.z, acc[i][3] + bv.w);
  }
}

// ---------- fused dual MFMA fp16 GEMM for gi + rowmax plane (y==24) ----------
__global__ __launch_bounds__(256) void k_mfma_gi2(
    const __half* __restrict__ A16,
    const __half* __restrict__ Wf_f, const __half* __restrict__ Wf_b,
    const float* __restrict__ bias_f, const float* __restrict__ bias_b,
    __half* __restrict__ Out_f, __half* __restrict__ Out_b,
    const float* __restrict__ h_x, float* __restrict__ h0) {
  const int N = 768;
  int y = blockIdx.y;
  if (y == 24) {  // rowmax plane: h0[b][j] = max_t h_x[b][t][j]
    int b = blockIdx.x;
    if (b >= NB) return;
    int j = threadIdx.x;
    float m = -INFINITY;
    for (int t = 0; t < LA; t++) m = fmaxf(m, h_x[((size_t)b * LA + t) * HDIM + j]);
    h0[b * HDIM + j] = m;
    return;
  }
  const __half* Wf = y < 12 ? Wf_f : Wf_b;
  const float* bias = y < 12 ? bias_f : bias_b;
  __half* Out = y < 12 ? Out_f : Out_b;
  int col0 = (y < 12 ? y : y - 12) * 64;
  int w = threadIdx.x >> 6, l = threadIdx.x & 63;
  int row0 = blockIdx.x * 64 + w * 16;
  int lr = l & 15, lg = l >> 4;
  f32x4 acc[4] = {};
  const __half* arow = A16 + (size_t)(row0 + lr) * 256 + lg * 8;
#pragma unroll
  for (int k0b = 0; k0b < 8; k0b++) {
    f16x8 a = *(const f16x8*)(arow + k0b * 32);
#pragma unroll
    for (int nt = 0; nt < 4; nt++) {
      int c = col0 + nt * 16 + lr;
      f16x8 b = *(const f16x8*)(Wf + ((size_t)(k0b * N + c) * 4 + lg) * 8);
      acc[nt] = __builtin_amdgcn_mfma_f32_16x16x32_f16(a, b, acc[nt], 0, 0, 0);
    }
  }
#pragma unroll
  for (int nt = 0; nt < 4; nt++) {
    int c = col0 + nt * 16 + lr;
    float bv = bias[c];
#pragma unroll
    for (int r = 0; r < 4; r++) {
      int row = row0 + lg * 4 + r;
      Out[(size_t)row * N + c] = __float2half(acc[nt][r] + bv);
    }
  }
}

// ---------- attention (round-14 proven) ----------
template <int LQ, int LK>
__global__ __launch_bounds__(128) void k_attn(
    float* __restrict__ q, const float* __restrict__ kbuf,
    const float* __restrict__ vbuf, const int* __restrict__ cq,
    const int* __restrict__ ck) {
  __shared__ float qs[LQ][65];
  __shared__ float ks[LK][65];
  __shared__ float vs[LK][65];
  int b = blockIdx.x, head = blockIdx.y;
  int tid = threadIdx.x;
  for (int idx = tid; idx < LQ * 16; idx += 128) {
    int i = idx >> 4, c = (idx & 15) * 4;
    float4 v = *(const float4*)(q + (size_t)(b * LQ + i) * HDIM + head * DKH + c);
    qs[i][c] = v.x; qs[i][c + 1] = v.y; qs[i][c + 2] = v.z; qs[i][c + 3] = v.w;
  }
  for (int idx = tid; idx < LK * 16; idx += 128) {
    int i = idx >> 4, c = (idx & 15) * 4;
    float4 v = *(const float4*)(kbuf + (size_t)(b * LK + i) * HDIM + head * DKH + c);
    ks[i][c] = v.x; ks[i][c + 1] = v.y; ks[i][c + 2] = v.z; ks[i][c + 3] = v.w;
    float4 w = *(const float4*)(vbuf + (size_t)(b * LK + i) * HDIM + head * DKH + c);
    vs[i][c] = w.x; vs[i][c + 1] = w.y; vs[i][c + 2] = w.z; vs[i][c + 3] = w.w;
  }
  __syncthreads();
  int nq = cq[b], nk = ck[b];
  for (int i = tid; i < LQ; i += 128) {
    float s[LK];
    float mx = -INFINITY;
    bool qv = i < nq;
#pragma unroll
    for (int k = 0; k < LK; k++) {
      float d = -1e9f;
      if (qv && k < nk) {
        float acc = 0.f;
        for (int c = 0; c < DKH; c++) acc += qs[i][c] * ks[k][c];
        d = acc * 0.125f;
      }
      s[k] = d;
      mx = fmaxf(mx, d);
    }
    float den = 0.f;
#pragma unroll
    for (int k = 0; k < LK; k++) { s[k] = expf(s[k] - mx); den += s[k]; }
    float inv = 1.0f / den;
    for (int c = 0; c < DKH; c++) {
      float acc = 0.f;
#pragma unroll
      for (int k = 0; k < LK; k++) acc += s[k] * vs[k][c];
      q[(size_t)(b * LQ + i) * HDIM + head * DKH + c] = acc * inv;
    }
  }
}

// ---------- GRU v4 (round-14 proven exact) ----------
__global__ __launch_bounds__(512, 2) void k_gru4(
    const float* __restrict__ h0, const __half* __restrict__ Wh_f,
    const __half* __restrict__ Wh_b, const __half* __restrict__ gi_f,
    const __half* __restrict__ gi_b, const float* __restrict__ bhh_f,
    const float* __restrict__ bhh_b, const int* __restrict__ ac,
    float* __restrict__ out) {
  int bid = blockIdx.x;
  int dir = bid & 1, pair = bid >> 1;
  int g0 = pair, g1 = pair + 128;
  int tid = threadIdx.x;
  int j = tid >> 1, half = tid & 1;
  const __half* W = dir ? Wh_b : Wh_f;
  const __half* gih = dir ? gi_b : gi_f;
  const float* bhh = dir ? bhh_b : bhh_f;

  F4H wr[16], wz[16], wn[16];
  {
    const float4* Wr4 = (const float4*)(W + (size_t)j * 256 + half * 128);
    const float4* Wz4 = (const float4*)(W + (size_t)(256 + j) * 256 + half * 128);
    const float4* Wn4 = (const float4*)(W + (size_t)(512 + j) * 256 + half * 128);
#pragma unroll
    for (int p = 0; p < 16; p++) wr[p].f4 = Wr4[p];
#pragma unroll
    for (int p = 0; p < 16; p++) wz[p].f4 = Wz4[p];
#pragma unroll
    for (int p = 0; p < 16; p++) wn[p].f4 = Wn4[p];
  }
  float br = bhh[j], bz = bhh[256 + j], bn = bhh[512 + j];
  int cnt = ac[g0];

  __shared__ __align__(16) __half hs[2][HDIM];
  float hprev0 = h0[(size_t)g0 * HDIM + j];
  float hprev1 = h0[(size_t)g1 * HDIM + j];
  if (half == 0) {
    hs[0][j] = __float2half(hprev0);
    hs[1][j] = __float2half(hprev1);
  }
  __syncthreads();

  const float4* h0p = (const float4*)hs[0] + half * 16;
  const float4* h1p = (const float4*)hs[1] + half * 16;
  float sum0 = 0.f, sum1 = 0.f;
  int nsteps = dir ? LA : cnt;
  for (int ti = 0; ti < nsteps; ti++) {
    int t = dir ? (LA - 1 - ti) : ti;
    const __half* gp0 = gih + ((size_t)g0 * LA + t) * 768 + j;
    const __half* gp1 = gih + ((size_t)g1 * LA + t) * 768 + j;
    float gr0 = __half2float(gp0[0]);
    float gz0 = __half2float(gp0[256]);
    float gn0 = __half2float(gp0[512]);
    float gr1 = __half2float(gp1[0]);
    float gz1 = __half2float(gp1[256]);
    float gn1 = __half2float(gp1[512]);
    float ap0 = 0.f, zp0 = 0.f, np0 = 0.f;
    float ap1 = 0.f, zp1 = 0.f, np1 = 0.f;
#pragma unroll
    for (int q = 0; q < 16; q++) {
      F4H hv0; hv0.f4 = h0p[q];
      F4H hv1; hv1.f4 = h1p[q];
#pragma unroll
      for (int u = 0; u < 4; u++) {
        ap0 = dot2acc(hv0.h[u], wr[q].h[u], ap0);
        zp0 = dot2acc(hv0.h[u], wz[q].h[u], zp0);
        np0 = dot2acc(hv0.h[u], wn[q].h[u], np0);
        ap1 = dot2acc(hv1.h[u], wr[q].h[u], ap1);
        zp1 = dot2acc(hv1.h[u], wz[q].h[u], zp1);
        np1 = dot2acc(hv1.h[u], wn[q].h[u], np1);
      }
    }
    ap0 += __shfl_xor(ap0, 1);
    zp0 += __shfl_xor(zp0, 1);
    np0 += __shfl_xor(np0, 1);
    ap1 += __shfl_xor(ap1, 1);
    zp1 += __shfl_xor(zp1, 1);
    np1 += __shfl_xor(np1, 1);
    float r0 = sigm(gr0 + br + ap0);
    float z0 = sigm(gz0 + bz + zp0);
    float n0 = tanh_fast(gn0 + bn + r0 * np0);
    float hnew0 = (1.f - z0) * n0 + z0 * hprev0;
    float r1 = sigm(gr1 + br + ap1);
    float z1 = sigm(gz1 + bz + zp1);
    float n1 = tanh_fast(gn1 + bn + r1 * np1);
    float hnew1 = (1.f - z1) * n1 + z1 * hprev1;
    __syncthreads();
    if (half == 0) {
      hs[0][j] = __float2half(hnew0);
      hs[1][j] = __float2half(hnew1);
    }
    hprev0 = hnew0;
    hprev1 = hnew1;
    if (t < cnt) { sum0 += hnew0; sum1 += hnew1; }
    __syncthreads();
  }
  if (half == 0) {
    out[(size_t)g0 * 512 + dir * 256 + j] = sum0 / (float)cnt;
    out[(size_t)g1 * 512 + dir * 256 + j] = sum1 / (float)cnt;
  }
}

extern "C" void kernel_launch(void* const* d_in, const int* in_sizes, int n_in,
                              void* d_out, int out_size, void* d_ws, size_t ws_size,
                              hipStream_t stream) {
  const float* atom_msg  = (const float*)d_in[0];
  const float* pharm_msg = (const float*)d_in[1];
  const float* hyper_msg = (const float*)d_in[2];
  const int* ac = (const int*)d_in[3];
  const int* pc = (const int*)d_in[4];
  const int* hc = (const int*)d_in[5];
  const float* p2h_Wq = (const float*)d_in[6];
  const float* p2h_bq = (const float*)d_in[7];
  const float* p2h_Wk = (const float*)d_in[8];
  const float* p2h_bk = (const float*)d_in[9];
  const float* p2h_Wv = (const float*)d_in[10];
  const float* p2h_bv = (const float*)d_in[11];
  const float* p2h_Wo = (const float*)d_in[12];
  const float* p2h_bo = (const float*)d_in[13];
  const float* a2p_Wq = (const float*)d_in[14];
  const float* a2p_bq = (const float*)d_in[15];
  const float* a2p_Wk = (const float*)d_in[16];
  const float* a2p_bk = (const float*)d_in[17];
  const float* a2p_Wv = (const float*)d_in[18];
  const float* a2p_bv = (const float*)d_in[19];
  const float* a2p_Wo = (const float*)d_in[20];
  const float* a2p_bo = (const float*)d_in[21];
  const float* Wih_f  = (const float*)d_in[22];
  const float* Whh_f  = (const float*)d_in[23];
  const float* bih_f  = (const float*)d_in[24];
  const float* bhh_f  = (const float*)d_in[25];
  const float* Wih_b  = (const float*)d_in[26];
  const float* Whh_b  = (const float*)d_in[27];
  const float* bih_b  = (const float*)d_in[28];
  const float* bhh_b  = (const float*)d_in[29];
  float* out = (float*)d_out;
  (void)in_sizes; (void)n_in; (void)out_size; (void)ws_size;

  char* wsb = (char*)d_ws;
  size_t off = 0;
  auto alloc = [&](size_t bytes) -> void* {
    void* p = wsb + off;
    off += (bytes + 255) & ~(size_t)255;
    return p;
  };
  const int MA = NB * LA, MP = NB * LP, MH = NB * LH;
  int* sa = (int*)alloc(NB * 4);
  int* sp = (int*)alloc(NB * 4);
  int* sh = (int*)alloc(NB * 4);
  __half* Wh16_f = (__half*)alloc((size_t)768 * 256 * 2);
  __half* Wh16_b = (__half*)alloc((size_t)768 * 256 * 2);
  __half* Wf16_f = (__half*)alloc((size_t)768 * 256 * 2);
  __half* Wf16_b = (__half*)alloc((size_t)768 * 256 * 2);
  float* q_p = (float*)alloc((size_t)MP * HDIM * 4);
  float* k_h = (float*)alloc((size_t)MH * HDIM * 4);
  float* v_h = (float*)alloc((size_t)MH * HDIM * 4);
  float* ph2 = (float*)alloc((size_t)MP * HDIM * 4);
  float* q_a = (float*)alloc((size_t)MA * HDIM * 4);
  float* k_p = (float*)alloc((size_t)MP * HDIM * 4);
  float* v_p = (float*)alloc((size_t)MP * HDIM * 4);
  float* h_x = (float*)alloc((size_t)MA * HDIM * 4);
  __half* h_x16 = (__half*)alloc((size_t)MA * HDIM * 2);
  float* h0  = (float*)alloc((size_t)NB * HDIM * 4);
  __half* gi_f = (__half*)alloc((size_t)MA * 768 * 2);
  __half* gi_b = (__half*)alloc((size_t)MA * 768 * 2);

  // 1. fused prep: scan + Whh cvt x2 + Wih pack x2
  {
    const int NT = 768 * 256;
    int blocks = 4 * NT / 256 + 1;
    k_prep<<<blocks, 256, 0, stream>>>(ac, pc, hc, sa, sp, sh,
        Whh_f, Wh16_f, Whh_b, Wh16_b, Wih_f, Wf16_f, Wih_b, Wf16_b);
  }

  // 2. MHA1 q/k/v in one dispatch (z=3)
  k_gemm_qkv<<<dim3(MP / 64, 4, 3), 256, 0, stream>>>(
      pharm_msg, sp, pc, LP, 1, MP, p2h_Wq, p2h_bq, q_p,
      hyper_msg, sh, hc, LH, 1, MH, p2h_Wk, p2h_bk, k_h,
      hyper_msg, sh, hc, LH, 1, MH, p2h_Wv, p2h_bv, v_h);
  // 3. attention 1
  k_attn<LP, LH><<<dim3(NB, NHEADS), 128, 0, stream>>>(q_p, k_h, v_h, pc, hc);
  // 4. o-proj 1 (+residual gather)
  k_gemm<false, true><<<dim3(MP / 64, 4), 256, 0, stream>>>(
      q_p, nullptr, sp, pc, LP, p2h_Wo, p2h_bo, pharm_msg, ph2, nullptr, 256);

  // 5. MHA2 q/k/v in one dispatch (q_a gathers atoms; k/v from ph2)
  k_gemm_qkv<<<dim3(MA / 64, 4, 3), 256, 0, stream>>>(
      atom_msg, sa, ac, LA, 1, MA, a2p_Wq, a2p_bq, q_a,
      ph2, nullptr, nullptr, 1, 0, MP, a2p_Wk, a2p_bk, k_p,
      ph2, nullptr, nullptr, 1, 0, MP, a2p_Wv, a2p_bv, v_p);
  // 6. attention 2
  k_attn<LA, LP><<<dim3(NB, NHEADS), 128, 0, stream>>>(q_a, k_p, v_p, ac, pc);
  // 7. o-proj 2 (+residual gather, + fp16 mirror for gi)
  k_gemm<false, true><<<dim3(MA / 64, 4), 256, 0, stream>>>(
      q_a, nullptr, sa, ac, LA, a2p_Wo, a2p_bo, atom_msg, h_x, h_x16, 256);

  // 8. gi (both dirs) + rowmax plane
  k_mfma_gi2<<<dim3(MA / 64, 25), 256, 0, stream>>>(
      h_x16, Wf16_f, Wf16_b, bih_f, bih_b, gi_f, gi_b, h_x, h0);
  // 9. GRU
  k_gru4<<<NB, 512, 0, stream>>>(h0, Wh16_f, Wh16_b, gi_f, gi_b, bhh_f, bhh_b, ac, out);
}